// Round 4
// baseline (1039.773 us; speedup 1.0000x reference)
//
#include <hip/hip_runtime.h>
#include <stdint.h>

// LRU forward: y = Re(scan(lam, gamma*(x@B^T)) @ C^T) + x @ D^T
// Round 4: pre-split weight hi/lo bf16 planes in ws (branch on ws_size, fallback =
// on-the-fly split), trunc-based h split. bf16x3 MFMA structure unchanged (LDR=40).

#define BSZ   8
#define TLEN  4096
#define DIN   1024
#define DOUT  1024
#define NST   512
#define M_TOT (BSZ * TLEN)   // 32768
#define NC    32
#define CL    128

#define LDR   40             // LDS row stride in shorts (80B) -> conflict-free writes

typedef __attribute__((ext_vector_type(8))) short bf16x8;
typedef __attribute__((ext_vector_type(4))) float f32x4;

// ---- bf16 helpers -------------------------------------------------------------------------
__device__ __forceinline__ float s2f(short s) {
  unsigned v = ((unsigned)(unsigned short)s) << 16;
  return __builtin_bit_cast(float, v);
}
__device__ __forceinline__ short f2s_rne(float f) {
  unsigned u = __builtin_bit_cast(unsigned, f);
  unsigned r = (u + 0x7FFFu + ((u >> 16) & 1u)) >> 16;
  return (short)r;
}
// h = truncated-bf16(f)  (residual exactly representable), l = RNE(f - h)
__device__ __forceinline__ void split(float f, short& h, short& l) {
  const unsigned u = __builtin_bit_cast(unsigned, f);
  h = (short)(u >> 16);
  const float fh = __builtin_bit_cast(float, u & 0xFFFF0000u);
  l = f2s_rne(f - fh);
}
__device__ __forceinline__ void split8(const float4 v0, const float4 v1, const float sgn,
                                       bf16x8& hv, bf16x8& lv) {
  const float f[8] = {v0.x, v0.y, v0.z, v0.w, v1.x, v1.y, v1.z, v1.w};
  #pragma unroll
  for (int j = 0; j < 8; ++j) { short hh, ll; split(sgn * f[j], hh, ll); hv[j] = hh; lv[j] = ll; }
}

// ---- MFMA compute for one staged K-step (BK=32): Ah*Bh + Ah*Bl + Al*Bh --------------------
__device__ __forceinline__ void mma_step(f32x4 (&acc)[4][4],
    const short* __restrict__ Ah, const short* __restrict__ Al,
    const short* __restrict__ Bh, const short* __restrict__ Bl,
    const int wm, const int wn, const int lane)
{
  const int lr = lane & 15, kg = lane >> 4;
  bf16x8 ah[4], al[4];
  #pragma unroll
  for (int mi = 0; mi < 4; ++mi) {
    const int ro = (wm * 64 + mi * 16 + lr) * LDR + kg * 8;
    ah[mi] = *(const bf16x8*)&Ah[ro];
    al[mi] = *(const bf16x8*)&Al[ro];
  }
  #pragma unroll
  for (int ni = 0; ni < 4; ++ni) {
    const int co = (wn * 64 + ni * 16 + lr) * LDR + kg * 8;
    const bf16x8 bh = *(const bf16x8*)&Bh[co];
    const bf16x8 bl = *(const bf16x8*)&Bl[co];
    #pragma unroll
    for (int mi = 0; mi < 4; ++mi) {
      acc[mi][ni] = __builtin_amdgcn_mfma_f32_16x16x32_bf16(ah[mi], bh, acc[mi][ni], 0, 0, 0);
      acc[mi][ni] = __builtin_amdgcn_mfma_f32_16x16x32_bf16(ah[mi], bl, acc[mi][ni], 0, 0, 0);
      acc[mi][ni] = __builtin_amdgcn_mfma_f32_16x16x32_bf16(al[mi], bh, acc[mi][ni], 0, 0, 0);
    }
  }
}

// ---- one GEMM phase (NT): APL/BPL select pre-split bf16 planes vs fp32+on-the-fly split ---
template<bool APL, bool BPL>
__device__ __forceinline__ void gemm_phase(
    const float* __restrict__ Af, const short* __restrict__ Aph, const short* __restrict__ Apl,
    const int lda,
    const float* __restrict__ Bf, const short* __restrict__ Bph, const short* __restrict__ Bpl,
    const int ldb, const float bsgn,
    const int K, const int m0, const int n0, const int tid,
    f32x4 (&acc)[4][4], short* Ah, short* Al, short* Bh, short* Bl)
{
  const int r    = tid & 127;
  const int kh   = tid >> 7;
  const int lane = tid & 63, w = tid >> 6, wm = w >> 1, wn = w & 1;

  float4 pa[4], pb[4];
  bf16x8 pah0, pah1, pal0, pal1;
  bf16x8 pbh0, pbh1, pbl0, pbl1;

  if constexpr (APL) {
    const size_t off = (size_t)(m0 + r) * lda + kh * 16;
    pah0 = *(const bf16x8*)(Aph + off); pah1 = *(const bf16x8*)(Aph + off + 8);
    pal0 = *(const bf16x8*)(Apl + off); pal1 = *(const bf16x8*)(Apl + off + 8);
  } else {
    const float* p = Af + (size_t)(m0 + r) * lda + kh * 16;
    #pragma unroll
    for (int i = 0; i < 4; ++i) pa[i] = *(const float4*)(p + 4 * i);
  }
  if constexpr (BPL) {
    const size_t off = (size_t)(n0 + r) * ldb + kh * 16;
    pbh0 = *(const bf16x8*)(Bph + off); pbh1 = *(const bf16x8*)(Bph + off + 8);
    pbl0 = *(const bf16x8*)(Bpl + off); pbl1 = *(const bf16x8*)(Bpl + off + 8);
  } else {
    const float* p = Bf + (size_t)(n0 + r) * ldb + kh * 16;
    #pragma unroll
    for (int i = 0; i < 4; ++i) pb[i] = *(const float4*)(p + 4 * i);
  }

  for (int k0 = 0; k0 < K; k0 += 32) {
    __syncthreads();                       // prior K-step's LDS reads complete
    const int wo = r * LDR + kh * 16;
    if constexpr (APL) {
      *(bf16x8*)&Ah[wo] = pah0;  *(bf16x8*)&Ah[wo + 8] = pah1;
      *(bf16x8*)&Al[wo] = pal0;  *(bf16x8*)&Al[wo + 8] = pal1;
    } else {
      bf16x8 hv0, lv0, hv1, lv1;
      split8(pa[0], pa[1], 1.0f, hv0, lv0);
      split8(pa[2], pa[3], 1.0f, hv1, lv1);
      *(bf16x8*)&Ah[wo] = hv0;  *(bf16x8*)&Ah[wo + 8] = hv1;
      *(bf16x8*)&Al[wo] = lv0;  *(bf16x8*)&Al[wo + 8] = lv1;
    }
    if constexpr (BPL) {
      *(bf16x8*)&Bh[wo] = pbh0;  *(bf16x8*)&Bh[wo + 8] = pbh1;
      *(bf16x8*)&Bl[wo] = pbl0;  *(bf16x8*)&Bl[wo + 8] = pbl1;
    } else {
      bf16x8 hv0, lv0, hv1, lv1;
      split8(pb[0], pb[1], bsgn, hv0, lv0);
      split8(pb[2], pb[3], bsgn, hv1, lv1);
      *(bf16x8*)&Bh[wo] = hv0;  *(bf16x8*)&Bh[wo + 8] = hv1;
      *(bf16x8*)&Bl[wo] = lv0;  *(bf16x8*)&Bl[wo + 8] = lv1;
    }
    __syncthreads();
    if (k0 + 32 < K) {                     // prefetch next K-tile, overlaps MFMA below
      if constexpr (APL) {
        const size_t off = (size_t)(m0 + r) * lda + (k0 + 32) + kh * 16;
        pah0 = *(const bf16x8*)(Aph + off); pah1 = *(const bf16x8*)(Aph + off + 8);
        pal0 = *(const bf16x8*)(Apl + off); pal1 = *(const bf16x8*)(Apl + off + 8);
      } else {
        const float* p = Af + (size_t)(m0 + r) * lda + (k0 + 32) + kh * 16;
        #pragma unroll
        for (int i = 0; i < 4; ++i) pa[i] = *(const float4*)(p + 4 * i);
      }
      if constexpr (BPL) {
        const size_t off = (size_t)(n0 + r) * ldb + (k0 + 32) + kh * 16;
        pbh0 = *(const bf16x8*)(Bph + off); pbh1 = *(const bf16x8*)(Bph + off + 8);
        pbl0 = *(const bf16x8*)(Bpl + off); pbl1 = *(const bf16x8*)(Bpl + off + 8);
      } else {
        const float* p = Bf + (size_t)(n0 + r) * ldb + (k0 + 32) + kh * 16;
        #pragma unroll
        for (int i = 0; i < 4; ++i) pb[i] = *(const float4*)(p + 4 * i);
      }
    }
    mma_step(acc, Ah, Al, Bh, Bl, wm, wn, lane);
  }
}

// ---- weight pre-split: planes = split(sgn * src) ------------------------------------------
__global__ __launch_bounds__(256) void wsplit_k(const float* __restrict__ src,
    short* __restrict__ h, short* __restrict__ l, const int n4, const float sgn)
{
  const int i = blockIdx.x * 256 + threadIdx.x;
  if (i >= n4) return;
  const float4 v = ((const float4*)src)[i];
  const float f[4] = {sgn * v.x, sgn * v.y, sgn * v.z, sgn * v.w};
  short4 hv, lv;
  split(f[0], hv.x, lv.x); split(f[1], hv.y, lv.y);
  split(f[2], hv.z, lv.z); split(f[3], hv.w, lv.w);
  ((short4*)h)[i] = hv;
  ((short4*)l)[i] = lv;
}

// ---- kernel 1: Bu planes = split_bf16(gamma * (x @ [Bre|Bim]^T)) --------------------------
template<bool WPL>
__global__ __launch_bounds__(256, 2) void bu_mfma(
    const float* __restrict__ x, const float* __restrict__ Bre, const float* __restrict__ Bim,
    const short* __restrict__ Breh, const short* __restrict__ Brel,
    const short* __restrict__ Bimh, const short* __restrict__ Biml,
    const float* __restrict__ gamma,
    short* __restrict__ re_h, short* __restrict__ re_l,
    short* __restrict__ im_h, short* __restrict__ im_l)
{
  __shared__ short Ah[128 * LDR], Al[128 * LDR], Bh[128 * LDR], Bl[128 * LDR];
  f32x4 acc[4][4] = {};
  const int tid = threadIdx.x;
  const int m0  = blockIdx.x * 128;
  const int n0s = blockIdx.y * 128;
  const bool re = (n0s < NST);
  const int nb0 = n0s & (NST - 1);

  gemm_phase<false, WPL>(x, nullptr, nullptr, DIN,
                         re ? Bre : Bim, re ? Breh : Bimh, re ? Brel : Biml, DIN, 1.0f,
                         DIN, m0, nb0, tid, acc, Ah, Al, Bh, Bl);

  short* Hp = re ? re_h : im_h;
  short* Lp = re ? re_l : im_l;
  const int lane = tid & 63, w = tid >> 6, wm = w >> 1, wn = w & 1;
  const int lr = lane & 15, lq = lane >> 4;
  #pragma unroll
  for (int ni = 0; ni < 4; ++ni) {
    const int nb = nb0 + wn * 64 + ni * 16 + lr;
    const float g = gamma[nb];
    #pragma unroll
    for (int mi = 0; mi < 4; ++mi)
      #pragma unroll
      for (int j = 0; j < 4; ++j) {
        const size_t m = (size_t)m0 + wm * 64 + mi * 16 + lq * 4 + j;
        short hh, ll;
        split(acc[mi][ni][j] * g, hh, ll);
        Hp[m * NST + nb] = hh;
        Lp[m * NST + nb] = ll;
      }
  }
}

// ---- scan params --------------------------------------------------------------------------
__global__ void params_k(const float* __restrict__ nulog, const float* __restrict__ thlog,
                         const float* __restrict__ glog,
                         float2* __restrict__ lam, float2* __restrict__ lamL,
                         float* __restrict__ gamma)
{
  const int n = blockIdx.x * 256 + threadIdx.x;
  if (n >= NST) return;
  const float nu = expf(nulog[n]);
  const float th = expf(thlog[n]);
  const float mod = expf(-nu);
  float s, c;
  sincosf(th, &s, &c);
  lam[n] = make_float2(mod * c, mod * s);
  const float modL = expf(-(float)CL * nu);
  float sL, cL;
  sincosf((float)CL * th, &sL, &cL);
  lamL[n] = make_float2(modL * cL, modL * sL);
  gamma[n] = expf(glog[n]);
}

// ---- scan phase 1: per-chunk local scan (zero init), emit chunk-final ---------------------
__global__ __launch_bounds__(256) void scan_partial(
    const short* __restrict__ re_h, const short* __restrict__ re_l,
    const short* __restrict__ im_h, const short* __restrict__ im_l,
    const float2* __restrict__ lam, float2* __restrict__ carry)
{
  const int g = blockIdx.x * 256 + threadIdx.x;
  const int n = g & (NST - 1);
  const int c = (g >> 9) & (NC - 1);
  const int b = g >> 14;
  const float2 L = lam[n];
  size_t idx = ((size_t)b * TLEN + (size_t)c * CL) * NST + n;
  float sr = 0.f, si = 0.f;
  #pragma unroll 4
  for (int t = 0; t < CL; ++t, idx += NST) {
    const float br = s2f(re_h[idx]) + s2f(re_l[idx]);
    const float bi = s2f(im_h[idx]) + s2f(im_l[idx]);
    const float nr = fmaf(L.x, sr, fmaf(-L.y, si, br));
    const float ni = fmaf(L.x, si, fmaf( L.y, sr, bi));
    sr = nr; si = ni;
  }
  carry[(size_t)(b * NC + c) * NST + n] = make_float2(sr, si);
}

// ---- scan phase 2: scan chunk summaries; leaves carry-IN per chunk ------------------------
__global__ __launch_bounds__(256) void scan_carry(
    float2* __restrict__ carry, const float2* __restrict__ lamL)
{
  const int g = blockIdx.x * 256 + threadIdx.x;
  const int n = g & (NST - 1);
  const int b = g >> 9;
  const float2 P = lamL[n];
  float sr = 0.f, si = 0.f;
  for (int c = 0; c < NC; ++c) {
    const size_t idx = (size_t)(b * NC + c) * NST + n;
    const float2 v = carry[idx];
    carry[idx] = make_float2(sr, si);
    const float nr = fmaf(P.x, sr, fmaf(-P.y, si, v.x));
    const float ni = fmaf(P.x, si, fmaf( P.y, sr, v.y));
    sr = nr; si = ni;
  }
}

// ---- scan phase 3: re-scan with carry-in, overwrite planes with state hi/lo ---------------
__global__ __launch_bounds__(256) void scan_final(
    short* __restrict__ re_h, short* __restrict__ re_l,
    short* __restrict__ im_h, short* __restrict__ im_l,
    const float2* __restrict__ lam, const float2* __restrict__ carry)
{
  const int g = blockIdx.x * 256 + threadIdx.x;
  const int n = g & (NST - 1);
  const int c = (g >> 9) & (NC - 1);
  const int b = g >> 14;
  const float2 L = lam[n];
  const float2 ci = carry[(size_t)(b * NC + c) * NST + n];
  size_t idx = ((size_t)b * TLEN + (size_t)c * CL) * NST + n;
  float sr = ci.x, si = ci.y;
  #pragma unroll 4
  for (int t = 0; t < CL; ++t, idx += NST) {
    const float br = s2f(re_h[idx]) + s2f(re_l[idx]);
    const float bi = s2f(im_h[idx]) + s2f(im_l[idx]);
    const float nr = fmaf(L.x, sr, fmaf(-L.y, si, br));
    const float ni = fmaf(L.x, si, fmaf( L.y, sr, bi));
    sr = nr; si = ni;
    short hh, ll;
    split(sr, hh, ll); re_h[idx] = hh; re_l[idx] = ll;
    split(si, hh, ll); im_h[idx] = hh; im_l[idx] = ll;
  }
}

// ---- kernel 5: y = st_re@Cre^T - st_im@Cim^T + x@D^T --------------------------------------
template<bool WPL>
__global__ __launch_bounds__(256, 2) void out_mfma(
    const short* __restrict__ re_h, const short* __restrict__ re_l,
    const short* __restrict__ im_h, const short* __restrict__ im_l,
    const float* __restrict__ x,
    const float* __restrict__ Cre, const float* __restrict__ Cim, const float* __restrict__ Dm,
    const short* __restrict__ Creh, const short* __restrict__ Crel,
    const short* __restrict__ Cimh, const short* __restrict__ Ciml,  // pre-negated
    const short* __restrict__ Dh,   const short* __restrict__ Dl,
    float* __restrict__ y)
{
  __shared__ short Ah[128 * LDR], Al[128 * LDR], Bh[128 * LDR], Bl[128 * LDR];
  f32x4 acc[4][4] = {};
  const int tid = threadIdx.x;
  const int m0 = blockIdx.x * 128;
  const int o0 = blockIdx.y * 128;

  gemm_phase<true,  WPL>(nullptr, re_h, re_l, NST, Cre, Creh, Crel, NST,  1.0f,
                         NST, m0, o0, tid, acc, Ah, Al, Bh, Bl);
  gemm_phase<true,  WPL>(nullptr, im_h, im_l, NST, Cim, Cimh, Ciml, NST, -1.0f,
                         NST, m0, o0, tid, acc, Ah, Al, Bh, Bl);
  gemm_phase<false, WPL>(x, nullptr, nullptr, DIN, Dm, Dh, Dl, DIN, 1.0f,
                         DIN, m0, o0, tid, acc, Ah, Al, Bh, Bl);

  const int lane = tid & 63, w = tid >> 6, wm = w >> 1, wn = w & 1;
  const int lr = lane & 15, lq = lane >> 4;
  #pragma unroll
  for (int mi = 0; mi < 4; ++mi)
    #pragma unroll
    for (int j = 0; j < 4; ++j) {
      const size_t m = (size_t)m0 + wm * 64 + mi * 16 + lq * 4 + j;
      #pragma unroll
      for (int ni = 0; ni < 4; ++ni)
        y[m * DOUT + o0 + wn * 64 + ni * 16 + lr] = acc[mi][ni][j];
    }
}

// ---- host launch --------------------------------------------------------------------------
extern "C" void kernel_launch(void* const* d_in, const int* in_sizes, int n_in,
                              void* d_out, int out_size, void* d_ws, size_t ws_size,
                              hipStream_t stream)
{
  (void)in_sizes; (void)n_in; (void)out_size;
  const float* x     = (const float*)d_in[0];
  const float* nulog = (const float*)d_in[1];
  const float* thlog = (const float*)d_in[2];
  const float* glog  = (const float*)d_in[3];
  const float* Bre   = (const float*)d_in[4];
  const float* Bim   = (const float*)d_in[5];
  const float* Cre   = (const float*)d_in[6];
  const float* Cim   = (const float*)d_in[7];
  const float* Dm    = (const float*)d_in[8];
  float* y = (float*)d_out;

  // base layout: 4 bf16 state planes | carry | lam | lamL | gamma
  const size_t PLANE = (size_t)M_TOT * NST;
  short*  re_h  = (short*)d_ws;
  short*  re_l  = re_h + PLANE;
  short*  im_h  = re_l + PLANE;
  short*  im_l  = im_h + PLANE;
  float2* carry = (float2*)(im_l + PLANE);
  float2* lam   = carry + (size_t)BSZ * NC * NST;
  float2* lamL  = lam + NST;
  float*  gamma = (float*)(lamL + NST);

  // optional weight-plane region (12 MB), used only if ws_size allows
  char* wp = (char*)(gamma + NST);
  wp = (char*)(((uintptr_t)wp + 255) & ~(uintptr_t)255);
  short* Breh = (short*)wp;
  short* Brel = Breh + (size_t)NST * DIN;
  short* Bimh = Brel + (size_t)NST * DIN;
  short* Biml = Bimh + (size_t)NST * DIN;
  short* Creh = Biml + (size_t)NST * DIN;
  short* Crel = Creh + (size_t)DOUT * NST;
  short* Cimh = Crel + (size_t)DOUT * NST;
  short* Ciml = Cimh + (size_t)DOUT * NST;
  short* Dh   = Ciml + (size_t)DOUT * NST;
  short* Dl   = Dh   + (size_t)DOUT * DIN;
  const size_t needed = (size_t)((char*)(Dl + (size_t)DOUT * DIN) - (char*)d_ws);
  const bool wpl = (ws_size >= needed);

  params_k<<<2, 256, 0, stream>>>(nulog, thlog, glog, lam, lamL, gamma);

  if (wpl) {
    const int nB4 = (NST * DIN) / 4, nC4 = (DOUT * NST) / 4, nD4 = (DOUT * DIN) / 4;
    wsplit_k<<<(nB4 + 255) / 256, 256, 0, stream>>>(Bre, Breh, Brel, nB4,  1.0f);
    wsplit_k<<<(nB4 + 255) / 256, 256, 0, stream>>>(Bim, Bimh, Biml, nB4,  1.0f);
    wsplit_k<<<(nC4 + 255) / 256, 256, 0, stream>>>(Cre, Creh, Crel, nC4,  1.0f);
    wsplit_k<<<(nC4 + 255) / 256, 256, 0, stream>>>(Cim, Cimh, Ciml, nC4, -1.0f);
    wsplit_k<<<(nD4 + 255) / 256, 256, 0, stream>>>(Dm,  Dh,   Dl,   nD4,  1.0f);
    bu_mfma<true><<<dim3(M_TOT / 128, (2 * NST) / 128), 256, 0, stream>>>(
        x, Bre, Bim, Breh, Brel, Bimh, Biml, gamma, re_h, re_l, im_h, im_l);
  } else {
    bu_mfma<false><<<dim3(M_TOT / 128, (2 * NST) / 128), 256, 0, stream>>>(
        x, Bre, Bim, Breh, Brel, Bimh, Biml, gamma, re_h, re_l, im_h, im_l);
  }

  scan_partial<<<(BSZ * NC * NST) / 256, 256, 0, stream>>>(re_h, re_l, im_h, im_l, lam, carry);
  scan_carry<<<(BSZ * NST) / 256, 256, 0, stream>>>(carry, lamL);
  scan_final<<<(BSZ * NC * NST) / 256, 256, 0, stream>>>(re_h, re_l, im_h, im_l, lam, carry);

  if (wpl) {
    out_mfma<true><<<dim3(M_TOT / 128, DOUT / 128), 256, 0, stream>>>(
        re_h, re_l, im_h, im_l, x, Cre, Cim, Dm,
        Creh, Crel, Cimh, Ciml, Dh, Dl, y);
  } else {
    out_mfma<false><<<dim3(M_TOT / 128, DOUT / 128), 256, 0, stream>>>(
        re_h, re_l, im_h, im_l, x, Cre, Cim, Dm,
        Creh, Crel, Cimh, Ciml, Dh, Dl, y);
  }
}

// Round 5
// 845.611 us; speedup vs baseline: 1.2296x; 1.2296x over previous
//
#include <hip/hip_runtime.h>
#include <stdint.h>

// LRU forward: y = Re(scan(lam, gamma*(x@B^T)) @ C^T) + x @ D^T
// Round 5: m97-style staging — all operands as pre-split bf16 hi/lo planes,
// global_load_lds (16B) into linear LDS with quad-XOR source swizzle
// (conflict-free reads), K-loop = {read frags; bar; stage k+1; MFMA; bar}.
// Fallback (ws too small for x planes): x reg-staged + split + swizzled ds_write.

#define BSZ   8
#define TLEN  4096
#define DIN   1024
#define DOUT  1024
#define NST   512
#define M_TOT (BSZ * TLEN)   // 32768
#define NC    32
#define CL    128

typedef __attribute__((ext_vector_type(8))) short bf16x8;
typedef __attribute__((ext_vector_type(4))) float f32x4;

// ---- bf16 helpers -------------------------------------------------------------------------
__device__ __forceinline__ float s2f(short s) {
  unsigned v = ((unsigned)(unsigned short)s) << 16;
  return __builtin_bit_cast(float, v);
}
__device__ __forceinline__ short f2s_rne(float f) {
  unsigned u = __builtin_bit_cast(unsigned, f);
  unsigned r = (u + 0x7FFFu + ((u >> 16) & 1u)) >> 16;
  return (short)r;
}
// h = truncated-bf16(f) (residual exactly representable), l = RNE(f - h)
__device__ __forceinline__ void split(float f, short& h, short& l) {
  const unsigned u = __builtin_bit_cast(unsigned, f);
  h = (short)(u >> 16);
  const float fh = __builtin_bit_cast(float, u & 0xFFFF0000u);
  l = f2s_rne(f - fh);
}
__device__ __forceinline__ void split8(const float4 v0, const float4 v1,
                                       bf16x8& hv, bf16x8& lv) {
  const float f[8] = {v0.x, v0.y, v0.z, v0.w, v1.x, v1.y, v1.z, v1.w};
  #pragma unroll
  for (int j = 0; j < 8; ++j) { short hh, ll; split(f[j], hh, ll); hv[j] = hh; lv[j] = ll; }
}

// ---- async global->LDS, 16B per lane ------------------------------------------------------
__device__ __forceinline__ void gload16(const short* g, short* l) {
  __builtin_amdgcn_global_load_lds(
      (const __attribute__((address_space(1))) void*)g,
      (__attribute__((address_space(3))) void*)l, 16, 0, 0);
}

// LDS tiles: linear [128][32] shorts (8 KB). Quad-XOR swizzle: data quad q of row r
// lives at slot quad q ^ ((r>>1)&3). global_load_lds writes slots linearly; the SOURCE
// address is permuted to match; ds_read applies the same XOR -> conflict-free.

// ---- stage one full plane (128 rows x 32 shorts) via 8 global_load_lds --------------------
__device__ __forceinline__ void stage_plane(const short* __restrict__ gp, const int r0,
                                            const int ld, const int k0,
                                            short* lp, const int lane)
{
  const int q  = (lane & 3) ^ ((lane >> 3) & 3);   // source quad for this slot
  const int gr = lane >> 2;                        // row within 16-row group
  const short* src = gp + (size_t)(r0 + gr) * ld + k0 + q * 8;
  #pragma unroll
  for (int i = 0; i < 8; ++i)
    gload16(src + (size_t)16 * i * ld, lp + i * 512);
}

// ---- stage all 4 planes: wave w -> plane w ------------------------------------------------
__device__ __forceinline__ void stage4(const short* Aph, const short* Apl,
    const short* Bph, const short* Bpl, const int lda, const int ldb,
    const int m0, const int n0, const int k0,
    short* Ah, short* Al, short* Bh, short* Bl, const int w, const int lane)
{
  if (w == 0)      stage_plane(Aph, m0, lda, k0, Ah, lane);
  else if (w == 1) stage_plane(Apl, m0, lda, k0, Al, lane);
  else if (w == 2) stage_plane(Bph, n0, ldb, k0, Bh, lane);
  else             stage_plane(Bpl, n0, ldb, k0, Bl, lane);
}

// ---- stage B planes only (x-fallback path): wave w -> half of plane (w&2 ? Bl : Bh) -------
__device__ __forceinline__ void stageB2(const short* Bph, const short* Bpl, const int ldb,
    const int n0, const int k0, short* Bh, short* Bl, const int w, const int lane)
{
  const int q  = (lane & 3) ^ ((lane >> 3) & 3);
  const int gr = lane >> 2;
  const short* gp = (w & 2) ? Bpl : Bph;
  short* lp = ((w & 2) ? Bl : Bh) + (w & 1) * 2048;
  const short* src = gp + (size_t)(n0 + (w & 1) * 64 + gr) * ldb + k0 + q * 8;
  #pragma unroll
  for (int i = 0; i < 4; ++i)
    gload16(src + (size_t)16 * i * ldb, lp + i * 512);
}

// ---- x-fallback: split fp32 regs -> swizzled ds_write -------------------------------------
__device__ __forceinline__ void stageAx(const float4 (&pa)[4], short* Ah, short* Al,
                                        const int r, const int kh)
{
  bf16x8 h0, l0, h1, l1;
  split8(pa[0], pa[1], h0, l0);
  split8(pa[2], pa[3], h1, l1);
  const int f  = (r >> 1) & 3;
  const int q0 = ((2 * kh) ^ f) * 8, q1 = ((2 * kh + 1) ^ f) * 8;
  *(bf16x8*)&Ah[r * 32 + q0] = h0;  *(bf16x8*)&Ah[r * 32 + q1] = h1;
  *(bf16x8*)&Al[r * 32 + q0] = l0;  *(bf16x8*)&Al[r * 32 + q1] = l1;
}

// ---- read all MFMA fragments for one K-step (swizzled ds_read_b128) -----------------------
__device__ __forceinline__ void read_frags(const short* Ah, const short* Al,
    const short* Bh, const short* Bl, const int wm, const int wn, const int lane,
    bf16x8 (&ah)[4], bf16x8 (&al)[4], bf16x8 (&bh)[4], bf16x8 (&bl)[4])
{
  const int lr = lane & 15, kg = lane >> 4;
  const int qo = (kg ^ ((lr >> 1) & 3)) * 8;
  #pragma unroll
  for (int mi = 0; mi < 4; ++mi) {
    const int ro = (wm * 64 + mi * 16 + lr) * 32 + qo;
    ah[mi] = *(const bf16x8*)&Ah[ro];
    al[mi] = *(const bf16x8*)&Al[ro];
  }
  #pragma unroll
  for (int ni = 0; ni < 4; ++ni) {
    const int co = (wn * 64 + ni * 16 + lr) * 32 + qo;
    bh[ni] = *(const bf16x8*)&Bh[co];
    bl[ni] = *(const bf16x8*)&Bl[co];
  }
}

// ---- 48 MFMA: Ah*Bh + Ah*Bl + Al*Bh -------------------------------------------------------
__device__ __forceinline__ void mma_frags(f32x4 (&acc)[4][4],
    const bf16x8 (&ah)[4], const bf16x8 (&al)[4],
    const bf16x8 (&bh)[4], const bf16x8 (&bl)[4])
{
  #pragma unroll
  for (int ni = 0; ni < 4; ++ni)
    #pragma unroll
    for (int mi = 0; mi < 4; ++mi) {
      acc[mi][ni] = __builtin_amdgcn_mfma_f32_16x16x32_bf16(ah[mi], bh[ni], acc[mi][ni], 0, 0, 0);
      acc[mi][ni] = __builtin_amdgcn_mfma_f32_16x16x32_bf16(ah[mi], bl[ni], acc[mi][ni], 0, 0, 0);
      acc[mi][ni] = __builtin_amdgcn_mfma_f32_16x16x32_bf16(al[mi], bh[ni], acc[mi][ni], 0, 0, 0);
    }
}

// ---- one GEMM phase over K. AG: A from bf16 planes via global_load_lds; else fp32+split ---
template<bool AG>
__device__ __forceinline__ void gemm_tile(
    const short* __restrict__ Aph, const short* __restrict__ Apl,
    const float* __restrict__ Af, const int lda,
    const short* __restrict__ Bph, const short* __restrict__ Bpl, const int ldb,
    const int K, const int m0, const int n0, const int tid,
    f32x4 (&acc)[4][4], short* Ah, short* Al, short* Bh, short* Bl)
{
  const int lane = tid & 63, w = tid >> 6, wm = w >> 1, wn = w & 1;
  const int r = tid & 127, kh = tid >> 7;
  float4 pa[4];

  // prologue: stage tile 0 (and prefetch x regs for tile 1 in fallback)
  if constexpr (AG) {
    stage4(Aph, Apl, Bph, Bpl, lda, ldb, m0, n0, 0, Ah, Al, Bh, Bl, w, lane);
  } else {
    const float* p = Af + (size_t)(m0 + r) * lda + kh * 16;
    #pragma unroll
    for (int i = 0; i < 4; ++i) pa[i] = *(const float4*)(p + 4 * i);
    stageAx(pa, Ah, Al, r, kh);
    stageB2(Bph, Bpl, ldb, n0, 0, Bh, Bl, w, lane);
    if (32 < K) {
      const float* p2 = Af + (size_t)(m0 + r) * lda + 32 + kh * 16;
      #pragma unroll
      for (int i = 0; i < 4; ++i) pa[i] = *(const float4*)(p2 + 4 * i);
    }
  }
  __syncthreads();   // drains stage-0 DMA

  for (int k0 = 0; k0 < K; k0 += 32) {
    bf16x8 ah[4], al[4], bh[4], bl[4];
    read_frags(Ah, Al, Bh, Bl, wm, wn, lane, ah, al, bh, bl);
    __syncthreads();                     // all waves done reading -> safe to overwrite
    if (k0 + 32 < K) {                   // stage next tile; flight overlaps MFMA below
      if constexpr (AG) {
        stage4(Aph, Apl, Bph, Bpl, lda, ldb, m0, n0, k0 + 32, Ah, Al, Bh, Bl, w, lane);
      } else {
        stageAx(pa, Ah, Al, r, kh);
        stageB2(Bph, Bpl, ldb, n0, k0 + 32, Bh, Bl, w, lane);
        if (k0 + 64 < K) {
          const float* p2 = Af + (size_t)(m0 + r) * lda + (k0 + 64) + kh * 16;
          #pragma unroll
          for (int i = 0; i < 4; ++i) pa[i] = *(const float4*)(p2 + 4 * i);
        }
      }
    }
    mma_frags(acc, ah, al, bh, bl);
    __syncthreads();                     // drains stage DMA -> next tile visible
  }
}

// ---- weight/x pre-split: planes = split(sgn * src) ----------------------------------------
__global__ __launch_bounds__(256) void wsplit_k(const float* __restrict__ src,
    short* __restrict__ h, short* __restrict__ l, const int n4, const float sgn)
{
  const int i = blockIdx.x * 256 + threadIdx.x;
  if (i >= n4) return;
  const float4 v = ((const float4*)src)[i];
  const float f[4] = {sgn * v.x, sgn * v.y, sgn * v.z, sgn * v.w};
  short4 hv, lv;
  split(f[0], hv.x, lv.x); split(f[1], hv.y, lv.y);
  split(f[2], hv.z, lv.z); split(f[3], hv.w, lv.w);
  ((short4*)h)[i] = hv;
  ((short4*)l)[i] = lv;
}

// ---- kernel 1: Bu planes = split_bf16(gamma * (x @ [Bre|Bim]^T)) --------------------------
template<bool XAG>
__global__ __launch_bounds__(256, 2) void bu_mfma(
    const float* __restrict__ x, const short* __restrict__ xh, const short* __restrict__ xl,
    const short* __restrict__ Brh, const short* __restrict__ Brl,
    const short* __restrict__ Bih, const short* __restrict__ Bil,
    const float* __restrict__ gamma,
    short* __restrict__ re_h, short* __restrict__ re_l,
    short* __restrict__ im_h, short* __restrict__ im_l)
{
  __shared__ short Ah[4096], Al[4096], Bh[4096], Bl[4096];
  f32x4 acc[4][4] = {};
  const int tid = threadIdx.x;
  const int m0  = blockIdx.x * 128;
  const int n0s = blockIdx.y * 128;
  const bool re = (n0s < NST);
  const int nb0 = n0s & (NST - 1);

  gemm_tile<XAG>(xh, xl, x, DIN, re ? Brh : Bih, re ? Brl : Bil, DIN,
                 DIN, m0, nb0, tid, acc, Ah, Al, Bh, Bl);

  short* Hp = re ? re_h : im_h;
  short* Lp = re ? re_l : im_l;
  const int lane = tid & 63, w = tid >> 6, wm = w >> 1, wn = w & 1;
  const int lr = lane & 15, lq = lane >> 4;
  #pragma unroll
  for (int ni = 0; ni < 4; ++ni) {
    const int nb = nb0 + wn * 64 + ni * 16 + lr;
    const float g = gamma[nb];
    #pragma unroll
    for (int mi = 0; mi < 4; ++mi)
      #pragma unroll
      for (int j = 0; j < 4; ++j) {
        const size_t m = (size_t)m0 + wm * 64 + mi * 16 + lq * 4 + j;
        short hh, ll;
        split(acc[mi][ni][j] * g, hh, ll);
        Hp[m * NST + nb] = hh;
        Lp[m * NST + nb] = ll;
      }
  }
}

// ---- scan params --------------------------------------------------------------------------
__global__ void params_k(const float* __restrict__ nulog, const float* __restrict__ thlog,
                         const float* __restrict__ glog,
                         float2* __restrict__ lam, float2* __restrict__ lamL,
                         float* __restrict__ gamma)
{
  const int n = blockIdx.x * 256 + threadIdx.x;
  if (n >= NST) return;
  const float nu = expf(nulog[n]);
  const float th = expf(thlog[n]);
  const float mod = expf(-nu);
  float s, c;
  sincosf(th, &s, &c);
  lam[n] = make_float2(mod * c, mod * s);
  const float modL = expf(-(float)CL * nu);
  float sL, cL;
  sincosf((float)CL * th, &sL, &cL);
  lamL[n] = make_float2(modL * cL, modL * sL);
  gamma[n] = expf(glog[n]);
}

// ---- scan phase 1 -------------------------------------------------------------------------
__global__ __launch_bounds__(256) void scan_partial(
    const short* __restrict__ re_h, const short* __restrict__ re_l,
    const short* __restrict__ im_h, const short* __restrict__ im_l,
    const float2* __restrict__ lam, float2* __restrict__ carry)
{
  const int g = blockIdx.x * 256 + threadIdx.x;
  const int n = g & (NST - 1);
  const int c = (g >> 9) & (NC - 1);
  const int b = g >> 14;
  const float2 L = lam[n];
  size_t idx = ((size_t)b * TLEN + (size_t)c * CL) * NST + n;
  float sr = 0.f, si = 0.f;
  #pragma unroll 4
  for (int t = 0; t < CL; ++t, idx += NST) {
    const float br = s2f(re_h[idx]) + s2f(re_l[idx]);
    const float bi = s2f(im_h[idx]) + s2f(im_l[idx]);
    const float nr = fmaf(L.x, sr, fmaf(-L.y, si, br));
    const float ni = fmaf(L.x, si, fmaf( L.y, sr, bi));
    sr = nr; si = ni;
  }
  carry[(size_t)(b * NC + c) * NST + n] = make_float2(sr, si);
}

// ---- scan phase 2 -------------------------------------------------------------------------
__global__ __launch_bounds__(256) void scan_carry(
    float2* __restrict__ carry, const float2* __restrict__ lamL)
{
  const int g = blockIdx.x * 256 + threadIdx.x;
  const int n = g & (NST - 1);
  const int b = g >> 9;
  const float2 P = lamL[n];
  float sr = 0.f, si = 0.f;
  for (int c = 0; c < NC; ++c) {
    const size_t idx = (size_t)(b * NC + c) * NST + n;
    const float2 v = carry[idx];
    carry[idx] = make_float2(sr, si);
    const float nr = fmaf(P.x, sr, fmaf(-P.y, si, v.x));
    const float ni = fmaf(P.x, si, fmaf( P.y, sr, v.y));
    sr = nr; si = ni;
  }
}

// ---- scan phase 3 -------------------------------------------------------------------------
__global__ __launch_bounds__(256) void scan_final(
    short* __restrict__ re_h, short* __restrict__ re_l,
    short* __restrict__ im_h, short* __restrict__ im_l,
    const float2* __restrict__ lam, const float2* __restrict__ carry)
{
  const int g = blockIdx.x * 256 + threadIdx.x;
  const int n = g & (NST - 1);
  const int c = (g >> 9) & (NC - 1);
  const int b = g >> 14;
  const float2 L = lam[n];
  const float2 ci = carry[(size_t)(b * NC + c) * NST + n];
  size_t idx = ((size_t)b * TLEN + (size_t)c * CL) * NST + n;
  float sr = ci.x, si = ci.y;
  #pragma unroll 4
  for (int t = 0; t < CL; ++t, idx += NST) {
    const float br = s2f(re_h[idx]) + s2f(re_l[idx]);
    const float bi = s2f(im_h[idx]) + s2f(im_l[idx]);
    const float nr = fmaf(L.x, sr, fmaf(-L.y, si, br));
    const float ni = fmaf(L.x, si, fmaf( L.y, sr, bi));
    sr = nr; si = ni;
    short hh, ll;
    split(sr, hh, ll); re_h[idx] = hh; re_l[idx] = ll;
    split(si, hh, ll); im_h[idx] = hh; im_l[idx] = ll;
  }
}

// ---- kernel 5: y = st_re@Cre^T - st_im@Cim^T + x@D^T --------------------------------------
template<bool XAG>
__global__ __launch_bounds__(256, 2) void out_mfma(
    const short* __restrict__ re_h, const short* __restrict__ re_l,
    const short* __restrict__ im_h, const short* __restrict__ im_l,
    const float* __restrict__ x, const short* __restrict__ xh, const short* __restrict__ xl,
    const short* __restrict__ Crh, const short* __restrict__ Crl,
    const short* __restrict__ Cih, const short* __restrict__ Cil,  // Cim pre-negated
    const short* __restrict__ Dh,  const short* __restrict__ Dl,
    float* __restrict__ y)
{
  __shared__ short Ah[4096], Al[4096], Bh[4096], Bl[4096];
  f32x4 acc[4][4] = {};
  const int tid = threadIdx.x;
  const int m0 = blockIdx.x * 128;
  const int o0 = blockIdx.y * 128;

  gemm_tile<true>(re_h, re_l, nullptr, NST, Crh, Crl, NST, NST, m0, o0, tid,
                  acc, Ah, Al, Bh, Bl);
  gemm_tile<true>(im_h, im_l, nullptr, NST, Cih, Cil, NST, NST, m0, o0, tid,
                  acc, Ah, Al, Bh, Bl);
  gemm_tile<XAG>(xh, xl, x, DIN, Dh, Dl, DIN, DIN, m0, o0, tid,
                 acc, Ah, Al, Bh, Bl);

  const int lane = tid & 63, w = tid >> 6, wm = w >> 1, wn = w & 1;
  const int lr = lane & 15, lq = lane >> 4;
  #pragma unroll
  for (int mi = 0; mi < 4; ++mi)
    #pragma unroll
    for (int j = 0; j < 4; ++j) {
      const size_t m = (size_t)m0 + wm * 64 + mi * 16 + lq * 4 + j;
      #pragma unroll
      for (int ni = 0; ni < 4; ++ni)
        y[m * DOUT + o0 + wn * 64 + ni * 16 + lr] = acc[mi][ni][j];
    }
}

// ---- host launch --------------------------------------------------------------------------
extern "C" void kernel_launch(void* const* d_in, const int* in_sizes, int n_in,
                              void* d_out, int out_size, void* d_ws, size_t ws_size,
                              hipStream_t stream)
{
  (void)in_sizes; (void)n_in; (void)out_size;
  const float* x     = (const float*)d_in[0];
  const float* nulog = (const float*)d_in[1];
  const float* thlog = (const float*)d_in[2];
  const float* glog  = (const float*)d_in[3];
  const float* Bre   = (const float*)d_in[4];
  const float* Bim   = (const float*)d_in[5];
  const float* Cre   = (const float*)d_in[6];
  const float* Cim   = (const float*)d_in[7];
  const float* Dm    = (const float*)d_in[8];
  float* y = (float*)d_out;

  // ws layout: 4 state planes | carry | lam | lamL | gamma | weight planes | [x planes]
  const size_t PLANE  = (size_t)M_TOT * NST;
  const size_t XPLANE = (size_t)M_TOT * DIN;
  short*  re_h  = (short*)d_ws;
  short*  re_l  = re_h + PLANE;
  short*  im_h  = re_l + PLANE;
  short*  im_l  = im_h + PLANE;
  float2* carry = (float2*)(im_l + PLANE);
  float2* lam   = carry + (size_t)BSZ * NC * NST;
  float2* lamL  = lam + NST;
  float*  gamma = (float*)(lamL + NST);

  char* wp = (char*)(gamma + NST);
  wp = (char*)(((uintptr_t)wp + 255) & ~(uintptr_t)255);
  short* Brh = (short*)wp;
  short* Brl = Brh + (size_t)NST * DIN;
  short* Bih = Brl + (size_t)NST * DIN;
  short* Bil = Bih + (size_t)NST * DIN;
  short* Crh = Bil + (size_t)NST * DIN;
  short* Crl = Crh + (size_t)DOUT * NST;
  short* Cih = Crl + (size_t)DOUT * NST;
  short* Cil = Cih + (size_t)DOUT * NST;
  short* Dh  = Cil + (size_t)DOUT * NST;
  short* Dl  = Dh  + (size_t)DOUT * DIN;
  short* xh  = Dl  + (size_t)DOUT * DIN;
  short* xl  = xh + XPLANE;
  const size_t needed_full = (size_t)((char*)(xl + XPLANE) - (char*)d_ws);
  const bool full = (ws_size >= needed_full);   // weights region proven to fit (round 4)

  params_k<<<2, 256, 0, stream>>>(nulog, thlog, glog, lam, lamL, gamma);

  const int nB4 = (NST * DIN) / 4, nC4 = (DOUT * NST) / 4, nD4 = (DOUT * DIN) / 4;
  wsplit_k<<<(nB4 + 255) / 256, 256, 0, stream>>>(Bre, Brh, Brl, nB4,  1.0f);
  wsplit_k<<<(nB4 + 255) / 256, 256, 0, stream>>>(Bim, Bih, Bil, nB4,  1.0f);
  wsplit_k<<<(nC4 + 255) / 256, 256, 0, stream>>>(Cre, Crh, Crl, nC4,  1.0f);
  wsplit_k<<<(nC4 + 255) / 256, 256, 0, stream>>>(Cim, Cih, Cil, nC4, -1.0f);
  wsplit_k<<<(nD4 + 255) / 256, 256, 0, stream>>>(Dm,  Dh,  Dl,  nD4,  1.0f);

  if (full) {
    const int nX4 = (int)(XPLANE / 4);
    wsplit_k<<<(nX4 + 255) / 256, 256, 0, stream>>>(x, xh, xl, nX4, 1.0f);
    bu_mfma<true><<<dim3(M_TOT / 128, (2 * NST) / 128), 256, 0, stream>>>(
        x, xh, xl, Brh, Brl, Bih, Bil, gamma, re_h, re_l, im_h, im_l);
  } else {
    bu_mfma<false><<<dim3(M_TOT / 128, (2 * NST) / 128), 256, 0, stream>>>(
        x, xh, xl, Brh, Brl, Bih, Bil, gamma, re_h, re_l, im_h, im_l);
  }

  scan_partial<<<(BSZ * NC * NST) / 256, 256, 0, stream>>>(re_h, re_l, im_h, im_l, lam, carry);
  scan_carry<<<(BSZ * NST) / 256, 256, 0, stream>>>(carry, lamL);
  scan_final<<<(BSZ * NC * NST) / 256, 256, 0, stream>>>(re_h, re_l, im_h, im_l, lam, carry);

  if (full) {
    out_mfma<true><<<dim3(M_TOT / 128, DOUT / 128), 256, 0, stream>>>(
        re_h, re_l, im_h, im_l, x, xh, xl, Crh, Crl, Cih, Cil, Dh, Dl, y);
  } else {
    out_mfma<false><<<dim3(M_TOT / 128, DOUT / 128), 256, 0, stream>>>(
        re_h, re_l, im_h, im_l, x, xh, xl, Crh, Crl, Cih, Cil, Dh, Dl, y);
  }
}

// Round 6
// 720.846 us; speedup vs baseline: 1.4424x; 1.1731x over previous
//
#include <hip/hip_runtime.h>
#include <stdint.h>

// LRU forward: y = Re(scan(lam, gamma*(x@B^T)) @ C^T) + x @ D^T
// Round 6: round-5 structure + XCD-locality block mapping (1D grid; each XCD owns a
// contiguous m-chunk; the 8 n-blocks of an m-group are adjacent -> A panels L2-hot).

#define BSZ   8
#define TLEN  4096
#define DIN   1024
#define DOUT  1024
#define NST   512
#define M_TOT (BSZ * TLEN)   // 32768
#define NC    32
#define CL    128

typedef __attribute__((ext_vector_type(8))) short bf16x8;
typedef __attribute__((ext_vector_type(4))) float f32x4;

// ---- bf16 helpers -------------------------------------------------------------------------
__device__ __forceinline__ float s2f(short s) {
  unsigned v = ((unsigned)(unsigned short)s) << 16;
  return __builtin_bit_cast(float, v);
}
__device__ __forceinline__ short f2s_rne(float f) {
  unsigned u = __builtin_bit_cast(unsigned, f);
  unsigned r = (u + 0x7FFFu + ((u >> 16) & 1u)) >> 16;
  return (short)r;
}
// h = truncated-bf16(f) (residual exactly representable), l = RNE(f - h)
__device__ __forceinline__ void split(float f, short& h, short& l) {
  const unsigned u = __builtin_bit_cast(unsigned, f);
  h = (short)(u >> 16);
  const float fh = __builtin_bit_cast(float, u & 0xFFFF0000u);
  l = f2s_rne(f - fh);
}
__device__ __forceinline__ void split8(const float4 v0, const float4 v1,
                                       bf16x8& hv, bf16x8& lv) {
  const float f[8] = {v0.x, v0.y, v0.z, v0.w, v1.x, v1.y, v1.z, v1.w};
  #pragma unroll
  for (int j = 0; j < 8; ++j) { short hh, ll; split(f[j], hh, ll); hv[j] = hh; lv[j] = ll; }
}

// ---- async global->LDS, 16B per lane ------------------------------------------------------
__device__ __forceinline__ void gload16(const short* g, short* l) {
  __builtin_amdgcn_global_load_lds(
      (const __attribute__((address_space(1))) void*)g,
      (__attribute__((address_space(3))) void*)l, 16, 0, 0);
}

// LDS tiles: linear [128][32] shorts (8 KB). Quad-XOR swizzle: data quad q of row r
// lives at slot quad q ^ ((r>>1)&3); source address permuted to match; ds_read applies
// the same XOR -> conflict-free (verified round 5: SQ_LDS_BANK_CONFLICT == 0).

// ---- stage one full plane (128 rows x 32 shorts) via 8 global_load_lds --------------------
__device__ __forceinline__ void stage_plane(const short* __restrict__ gp, const int r0,
                                            const int ld, const int k0,
                                            short* lp, const int lane)
{
  const int q  = (lane & 3) ^ ((lane >> 3) & 3);   // source quad for this slot
  const int gr = lane >> 2;                        // row within 16-row group
  const short* src = gp + (size_t)(r0 + gr) * ld + k0 + q * 8;
  #pragma unroll
  for (int i = 0; i < 8; ++i)
    gload16(src + (size_t)16 * i * ld, lp + i * 512);
}

// ---- stage all 4 planes: wave w -> plane w ------------------------------------------------
__device__ __forceinline__ void stage4(const short* Aph, const short* Apl,
    const short* Bph, const short* Bpl, const int lda, const int ldb,
    const int m0, const int n0, const int k0,
    short* Ah, short* Al, short* Bh, short* Bl, const int w, const int lane)
{
  if (w == 0)      stage_plane(Aph, m0, lda, k0, Ah, lane);
  else if (w == 1) stage_plane(Apl, m0, lda, k0, Al, lane);
  else if (w == 2) stage_plane(Bph, n0, ldb, k0, Bh, lane);
  else             stage_plane(Bpl, n0, ldb, k0, Bl, lane);
}

// ---- stage B planes only (x-fallback path) ------------------------------------------------
__device__ __forceinline__ void stageB2(const short* Bph, const short* Bpl, const int ldb,
    const int n0, const int k0, short* Bh, short* Bl, const int w, const int lane)
{
  const int q  = (lane & 3) ^ ((lane >> 3) & 3);
  const int gr = lane >> 2;
  const short* gp = (w & 2) ? Bpl : Bph;
  short* lp = ((w & 2) ? Bl : Bh) + (w & 1) * 2048;
  const short* src = gp + (size_t)(n0 + (w & 1) * 64 + gr) * ldb + k0 + q * 8;
  #pragma unroll
  for (int i = 0; i < 4; ++i)
    gload16(src + (size_t)16 * i * ldb, lp + i * 512);
}

// ---- x-fallback: split fp32 regs -> swizzled ds_write -------------------------------------
__device__ __forceinline__ void stageAx(const float4 (&pa)[4], short* Ah, short* Al,
                                        const int r, const int kh)
{
  bf16x8 h0, l0, h1, l1;
  split8(pa[0], pa[1], h0, l0);
  split8(pa[2], pa[3], h1, l1);
  const int f  = (r >> 1) & 3;
  const int q0 = ((2 * kh) ^ f) * 8, q1 = ((2 * kh + 1) ^ f) * 8;
  *(bf16x8*)&Ah[r * 32 + q0] = h0;  *(bf16x8*)&Ah[r * 32 + q1] = h1;
  *(bf16x8*)&Al[r * 32 + q0] = l0;  *(bf16x8*)&Al[r * 32 + q1] = l1;
}

// ---- read all MFMA fragments for one K-step (swizzled ds_read_b128) -----------------------
__device__ __forceinline__ void read_frags(const short* Ah, const short* Al,
    const short* Bh, const short* Bl, const int wm, const int wn, const int lane,
    bf16x8 (&ah)[4], bf16x8 (&al)[4], bf16x8 (&bh)[4], bf16x8 (&bl)[4])
{
  const int lr = lane & 15, kg = lane >> 4;
  const int qo = (kg ^ ((lr >> 1) & 3)) * 8;
  #pragma unroll
  for (int mi = 0; mi < 4; ++mi) {
    const int ro = (wm * 64 + mi * 16 + lr) * 32 + qo;
    ah[mi] = *(const bf16x8*)&Ah[ro];
    al[mi] = *(const bf16x8*)&Al[ro];
  }
  #pragma unroll
  for (int ni = 0; ni < 4; ++ni) {
    const int co = (wn * 64 + ni * 16 + lr) * 32 + qo;
    bh[ni] = *(const bf16x8*)&Bh[co];
    bl[ni] = *(const bf16x8*)&Bl[co];
  }
}

// ---- 48 MFMA: Ah*Bh + Ah*Bl + Al*Bh -------------------------------------------------------
__device__ __forceinline__ void mma_frags(f32x4 (&acc)[4][4],
    const bf16x8 (&ah)[4], const bf16x8 (&al)[4],
    const bf16x8 (&bh)[4], const bf16x8 (&bl)[4])
{
  #pragma unroll
  for (int ni = 0; ni < 4; ++ni)
    #pragma unroll
    for (int mi = 0; mi < 4; ++mi) {
      acc[mi][ni] = __builtin_amdgcn_mfma_f32_16x16x32_bf16(ah[mi], bh[ni], acc[mi][ni], 0, 0, 0);
      acc[mi][ni] = __builtin_amdgcn_mfma_f32_16x16x32_bf16(ah[mi], bl[ni], acc[mi][ni], 0, 0, 0);
      acc[mi][ni] = __builtin_amdgcn_mfma_f32_16x16x32_bf16(al[mi], bh[ni], acc[mi][ni], 0, 0, 0);
    }
}

// ---- one GEMM phase over K. AG: A from bf16 planes via global_load_lds; else fp32+split ---
template<bool AG>
__device__ __forceinline__ void gemm_tile(
    const short* __restrict__ Aph, const short* __restrict__ Apl,
    const float* __restrict__ Af, const int lda,
    const short* __restrict__ Bph, const short* __restrict__ Bpl, const int ldb,
    const int K, const int m0, const int n0, const int tid,
    f32x4 (&acc)[4][4], short* Ah, short* Al, short* Bh, short* Bl)
{
  const int lane = tid & 63, w = tid >> 6, wm = w >> 1, wn = w & 1;
  const int r = tid & 127, kh = tid >> 7;
  float4 pa[4];

  if constexpr (AG) {
    stage4(Aph, Apl, Bph, Bpl, lda, ldb, m0, n0, 0, Ah, Al, Bh, Bl, w, lane);
  } else {
    const float* p = Af + (size_t)(m0 + r) * lda + kh * 16;
    #pragma unroll
    for (int i = 0; i < 4; ++i) pa[i] = *(const float4*)(p + 4 * i);
    stageAx(pa, Ah, Al, r, kh);
    stageB2(Bph, Bpl, ldb, n0, 0, Bh, Bl, w, lane);
    if (32 < K) {
      const float* p2 = Af + (size_t)(m0 + r) * lda + 32 + kh * 16;
      #pragma unroll
      for (int i = 0; i < 4; ++i) pa[i] = *(const float4*)(p2 + 4 * i);
    }
  }
  __syncthreads();   // drains stage-0 DMA

  for (int k0 = 0; k0 < K; k0 += 32) {
    bf16x8 ah[4], al[4], bh[4], bl[4];
    read_frags(Ah, Al, Bh, Bl, wm, wn, lane, ah, al, bh, bl);
    __syncthreads();                     // all waves done reading -> safe to overwrite
    if (k0 + 32 < K) {                   // stage next tile; flight overlaps MFMA below
      if constexpr (AG) {
        stage4(Aph, Apl, Bph, Bpl, lda, ldb, m0, n0, k0 + 32, Ah, Al, Bh, Bl, w, lane);
      } else {
        stageAx(pa, Ah, Al, r, kh);
        stageB2(Bph, Bpl, ldb, n0, k0 + 32, Bh, Bl, w, lane);
        if (k0 + 64 < K) {
          const float* p2 = Af + (size_t)(m0 + r) * lda + (k0 + 64) + kh * 16;
          #pragma unroll
          for (int i = 0; i < 4; ++i) pa[i] = *(const float4*)(p2 + 4 * i);
        }
      }
    }
    mma_frags(acc, ah, al, bh, bl);
    __syncthreads();                     // drains stage DMA -> next tile visible
  }
}

// ---- XCD-locality block mapping: bid -> (m_blk, n_blk) ------------------------------------
// Round-robin XCD dispatch assumed (perf-only). Each XCD owns 32 consecutive m-blocks;
// the 8 n-blocks of one m-group are adjacent in its local stream -> A panel L2-hot.
__device__ __forceinline__ void map_mn(const int bid, int& mb, int& nb) {
  const int xcd = bid & 7;
  const int j   = bid >> 3;       // 0..255
  mb = xcd * 32 + (j >> 3);       // 0..255
  nb = j & 7;                     // 0..7
}

// ---- weight/x pre-split: planes = split(sgn * src) ----------------------------------------
__global__ __launch_bounds__(256) void wsplit_k(const float* __restrict__ src,
    short* __restrict__ h, short* __restrict__ l, const int n4, const float sgn)
{
  const int i = blockIdx.x * 256 + threadIdx.x;
  if (i >= n4) return;
  const float4 v = ((const float4*)src)[i];
  const float f[4] = {sgn * v.x, sgn * v.y, sgn * v.z, sgn * v.w};
  short4 hv, lv;
  split(f[0], hv.x, lv.x); split(f[1], hv.y, lv.y);
  split(f[2], hv.z, lv.z); split(f[3], hv.w, lv.w);
  ((short4*)h)[i] = hv;
  ((short4*)l)[i] = lv;
}

// ---- kernel 1: Bu planes = split_bf16(gamma * (x @ [Bre|Bim]^T)) --------------------------
template<bool XAG>
__global__ __launch_bounds__(256, 2) void bu_mfma(
    const float* __restrict__ x, const short* __restrict__ xh, const short* __restrict__ xl,
    const short* __restrict__ Brh, const short* __restrict__ Brl,
    const short* __restrict__ Bih, const short* __restrict__ Bil,
    const float* __restrict__ gamma,
    short* __restrict__ re_h, short* __restrict__ re_l,
    short* __restrict__ im_h, short* __restrict__ im_l)
{
  __shared__ short Ah[4096], Al[4096], Bh[4096], Bl[4096];
  f32x4 acc[4][4] = {};
  const int tid = threadIdx.x;
  int mb, nbk;
  map_mn(blockIdx.x, mb, nbk);
  const int m0  = mb * 128;
  const int n0s = nbk * 128;
  const bool re = (n0s < NST);
  const int nb0 = n0s & (NST - 1);

  gemm_tile<XAG>(xh, xl, x, DIN, re ? Brh : Bih, re ? Brl : Bil, DIN,
                 DIN, m0, nb0, tid, acc, Ah, Al, Bh, Bl);

  short* Hp = re ? re_h : im_h;
  short* Lp = re ? re_l : im_l;
  const int lane = tid & 63, w = tid >> 6, wm = w >> 1, wn = w & 1;
  const int lr = lane & 15, lq = lane >> 4;
  #pragma unroll
  for (int ni = 0; ni < 4; ++ni) {
    const int nb = nb0 + wn * 64 + ni * 16 + lr;
    const float g = gamma[nb];
    #pragma unroll
    for (int mi = 0; mi < 4; ++mi)
      #pragma unroll
      for (int j = 0; j < 4; ++j) {
        const size_t m = (size_t)m0 + wm * 64 + mi * 16 + lq * 4 + j;
        short hh, ll;
        split(acc[mi][ni][j] * g, hh, ll);
        Hp[m * NST + nb] = hh;
        Lp[m * NST + nb] = ll;
      }
  }
}

// ---- scan params --------------------------------------------------------------------------
__global__ void params_k(const float* __restrict__ nulog, const float* __restrict__ thlog,
                         const float* __restrict__ glog,
                         float2* __restrict__ lam, float2* __restrict__ lamL,
                         float* __restrict__ gamma)
{
  const int n = blockIdx.x * 256 + threadIdx.x;
  if (n >= NST) return;
  const float nu = expf(nulog[n]);
  const float th = expf(thlog[n]);
  const float mod = expf(-nu);
  float s, c;
  sincosf(th, &s, &c);
  lam[n] = make_float2(mod * c, mod * s);
  const float modL = expf(-(float)CL * nu);
  float sL, cL;
  sincosf((float)CL * th, &sL, &cL);
  lamL[n] = make_float2(modL * cL, modL * sL);
  gamma[n] = expf(glog[n]);
}

// ---- scan phase 1 -------------------------------------------------------------------------
__global__ __launch_bounds__(256) void scan_partial(
    const short* __restrict__ re_h, const short* __restrict__ re_l,
    const short* __restrict__ im_h, const short* __restrict__ im_l,
    const float2* __restrict__ lam, float2* __restrict__ carry)
{
  const int g = blockIdx.x * 256 + threadIdx.x;
  const int n = g & (NST - 1);
  const int c = (g >> 9) & (NC - 1);
  const int b = g >> 14;
  const float2 L = lam[n];
  size_t idx = ((size_t)b * TLEN + (size_t)c * CL) * NST + n;
  float sr = 0.f, si = 0.f;
  #pragma unroll 4
  for (int t = 0; t < CL; ++t, idx += NST) {
    const float br = s2f(re_h[idx]) + s2f(re_l[idx]);
    const float bi = s2f(im_h[idx]) + s2f(im_l[idx]);
    const float nr = fmaf(L.x, sr, fmaf(-L.y, si, br));
    const float ni = fmaf(L.x, si, fmaf( L.y, sr, bi));
    sr = nr; si = ni;
  }
  carry[(size_t)(b * NC + c) * NST + n] = make_float2(sr, si);
}

// ---- scan phase 2 -------------------------------------------------------------------------
__global__ __launch_bounds__(256) void scan_carry(
    float2* __restrict__ carry, const float2* __restrict__ lamL)
{
  const int g = blockIdx.x * 256 + threadIdx.x;
  const int n = g & (NST - 1);
  const int b = g >> 9;
  const float2 P = lamL[n];
  float sr = 0.f, si = 0.f;
  for (int c = 0; c < NC; ++c) {
    const size_t idx = (size_t)(b * NC + c) * NST + n;
    const float2 v = carry[idx];
    carry[idx] = make_float2(sr, si);
    const float nr = fmaf(P.x, sr, fmaf(-P.y, si, v.x));
    const float ni = fmaf(P.x, si, fmaf( P.y, sr, v.y));
    sr = nr; si = ni;
  }
}

// ---- scan phase 3 -------------------------------------------------------------------------
__global__ __launch_bounds__(256) void scan_final(
    short* __restrict__ re_h, short* __restrict__ re_l,
    short* __restrict__ im_h, short* __restrict__ im_l,
    const float2* __restrict__ lam, const float2* __restrict__ carry)
{
  const int g = blockIdx.x * 256 + threadIdx.x;
  const int n = g & (NST - 1);
  const int c = (g >> 9) & (NC - 1);
  const int b = g >> 14;
  const float2 L = lam[n];
  const float2 ci = carry[(size_t)(b * NC + c) * NST + n];
  size_t idx = ((size_t)b * TLEN + (size_t)c * CL) * NST + n;
  float sr = ci.x, si = ci.y;
  #pragma unroll 4
  for (int t = 0; t < CL; ++t, idx += NST) {
    const float br = s2f(re_h[idx]) + s2f(re_l[idx]);
    const float bi = s2f(im_h[idx]) + s2f(im_l[idx]);
    const float nr = fmaf(L.x, sr, fmaf(-L.y, si, br));
    const float ni = fmaf(L.x, si, fmaf( L.y, sr, bi));
    sr = nr; si = ni;
    short hh, ll;
    split(sr, hh, ll); re_h[idx] = hh; re_l[idx] = ll;
    split(si, hh, ll); im_h[idx] = hh; im_l[idx] = ll;
  }
}

// ---- kernel 5: y = st_re@Cre^T - st_im@Cim^T + x@D^T --------------------------------------
template<bool XAG>
__global__ __launch_bounds__(256, 2) void out_mfma(
    const short* __restrict__ re_h, const short* __restrict__ re_l,
    const short* __restrict__ im_h, const short* __restrict__ im_l,
    const float* __restrict__ x, const short* __restrict__ xh, const short* __restrict__ xl,
    const short* __restrict__ Crh, const short* __restrict__ Crl,
    const short* __restrict__ Cih, const short* __restrict__ Cil,  // Cim pre-negated
    const short* __restrict__ Dh,  const short* __restrict__ Dl,
    float* __restrict__ y)
{
  __shared__ short Ah[4096], Al[4096], Bh[4096], Bl[4096];
  f32x4 acc[4][4] = {};
  const int tid = threadIdx.x;
  int mb, nbk;
  map_mn(blockIdx.x, mb, nbk);
  const int m0 = mb * 128;
  const int o0 = nbk * 128;

  gemm_tile<true>(re_h, re_l, nullptr, NST, Crh, Crl, NST, NST, m0, o0, tid,
                  acc, Ah, Al, Bh, Bl);
  gemm_tile<true>(im_h, im_l, nullptr, NST, Cih, Cil, NST, NST, m0, o0, tid,
                  acc, Ah, Al, Bh, Bl);
  gemm_tile<XAG>(xh, xl, x, DIN, Dh, Dl, DIN, DIN, m0, o0, tid,
                 acc, Ah, Al, Bh, Bl);

  const int lane = tid & 63, w = tid >> 6, wm = w >> 1, wn = w & 1;
  const int lr = lane & 15, lq = lane >> 4;
  #pragma unroll
  for (int mi = 0; mi < 4; ++mi)
    #pragma unroll
    for (int j = 0; j < 4; ++j) {
      const size_t m = (size_t)m0 + wm * 64 + mi * 16 + lq * 4 + j;
      #pragma unroll
      for (int ni = 0; ni < 4; ++ni)
        y[m * DOUT + o0 + wn * 64 + ni * 16 + lr] = acc[mi][ni][j];
    }
}

// ---- host launch --------------------------------------------------------------------------
extern "C" void kernel_launch(void* const* d_in, const int* in_sizes, int n_in,
                              void* d_out, int out_size, void* d_ws, size_t ws_size,
                              hipStream_t stream)
{
  (void)in_sizes; (void)n_in; (void)out_size;
  const float* x     = (const float*)d_in[0];
  const float* nulog = (const float*)d_in[1];
  const float* thlog = (const float*)d_in[2];
  const float* glog  = (const float*)d_in[3];
  const float* Bre   = (const float*)d_in[4];
  const float* Bim   = (const float*)d_in[5];
  const float* Cre   = (const float*)d_in[6];
  const float* Cim   = (const float*)d_in[7];
  const float* Dm    = (const float*)d_in[8];
  float* y = (float*)d_out;

  // ws layout: 4 state planes | carry | lam | lamL | gamma | weight planes | [x planes]
  const size_t PLANE  = (size_t)M_TOT * NST;
  const size_t XPLANE = (size_t)M_TOT * DIN;
  short*  re_h  = (short*)d_ws;
  short*  re_l  = re_h + PLANE;
  short*  im_h  = re_l + PLANE;
  short*  im_l  = im_h + PLANE;
  float2* carry = (float2*)(im_l + PLANE);
  float2* lam   = carry + (size_t)BSZ * NC * NST;
  float2* lamL  = lam + NST;
  float*  gamma = (float*)(lamL + NST);

  char* wp = (char*)(gamma + NST);
  wp = (char*)(((uintptr_t)wp + 255) & ~(uintptr_t)255);
  short* Brh = (short*)wp;
  short* Brl = Brh + (size_t)NST * DIN;
  short* Bih = Brl + (size_t)NST * DIN;
  short* Bil = Bih + (size_t)NST * DIN;
  short* Crh = Bil + (size_t)NST * DIN;
  short* Crl = Crh + (size_t)DOUT * NST;
  short* Cih = Crl + (size_t)DOUT * NST;
  short* Cil = Cih + (size_t)DOUT * NST;
  short* Dh  = Cil + (size_t)DOUT * NST;
  short* Dl  = Dh  + (size_t)DOUT * DIN;
  short* xh  = Dl  + (size_t)DOUT * DIN;
  short* xl  = xh + XPLANE;
  const size_t needed_full = (size_t)((char*)(xl + XPLANE) - (char*)d_ws);
  const bool full = (ws_size >= needed_full);

  params_k<<<2, 256, 0, stream>>>(nulog, thlog, glog, lam, lamL, gamma);

  const int nB4 = (NST * DIN) / 4, nC4 = (DOUT * NST) / 4, nD4 = (DOUT * DIN) / 4;
  wsplit_k<<<(nB4 + 255) / 256, 256, 0, stream>>>(Bre, Brh, Brl, nB4,  1.0f);
  wsplit_k<<<(nB4 + 255) / 256, 256, 0, stream>>>(Bim, Bih, Bil, nB4,  1.0f);
  wsplit_k<<<(nC4 + 255) / 256, 256, 0, stream>>>(Cre, Crh, Crl, nC4,  1.0f);
  wsplit_k<<<(nC4 + 255) / 256, 256, 0, stream>>>(Cim, Cih, Cil, nC4, -1.0f);
  wsplit_k<<<(nD4 + 255) / 256, 256, 0, stream>>>(Dm,  Dh,  Dl,  nD4,  1.0f);

  if (full) {
    const int nX4 = (int)(XPLANE / 4);
    wsplit_k<<<(nX4 + 255) / 256, 256, 0, stream>>>(x, xh, xl, nX4, 1.0f);
    bu_mfma<true><<<2048, 256, 0, stream>>>(
        x, xh, xl, Brh, Brl, Bih, Bil, gamma, re_h, re_l, im_h, im_l);
  } else {
    bu_mfma<false><<<2048, 256, 0, stream>>>(
        x, xh, xl, Brh, Brl, Bih, Bil, gamma, re_h, re_l, im_h, im_l);
  }

  scan_partial<<<(BSZ * NC * NST) / 256, 256, 0, stream>>>(re_h, re_l, im_h, im_l, lam, carry);
  scan_carry<<<(BSZ * NST) / 256, 256, 0, stream>>>(carry, lamL);
  scan_final<<<(BSZ * NC * NST) / 256, 256, 0, stream>>>(re_h, re_l, im_h, im_l, lam, carry);

  if (full) {
    out_mfma<true><<<2048, 256, 0, stream>>>(
        re_h, re_l, im_h, im_l, x, xh, xl, Crh, Crl, Cih, Cil, Dh, Dl, y);
  } else {
    out_mfma<false><<<2048, 256, 0, stream>>>(
        re_h, re_l, im_h, im_l, x, xh, xl, Crh, Crl, Cih, Cil, Dh, Dl, y);
  }
}

// Round 7
// 629.039 us; speedup vs baseline: 1.6530x; 1.1459x over previous
//
#include <hip/hip_runtime.h>
#include <stdint.h>

// LRU forward: y = Re(scan(lam, gamma*(x@B^T)) @ C^T) + x @ D^T
// Round 7: (1) double-buffered LDS + raw s_barrier + counted vmcnt (T3/T4-lite,
// 2-deep DMA prefetch, never drain-to-0 mid-loop); (2) bf16x2 for B/D weight
// phases (single RNE plane, 2 MFMA), C stays hi/lo (3 MFMA) to protect absmax.

#define BSZ   8
#define TLEN  4096
#define DIN   1024
#define DOUT  1024
#define NST   512
#define M_TOT (BSZ * TLEN)   // 32768
#define NC    32
#define CL    128
#define PL    4096           // LDS plane: 128 rows x 32 shorts (8 KB)

typedef __attribute__((ext_vector_type(8))) short bf16x8;
typedef __attribute__((ext_vector_type(4))) float f32x4;

// ---- bf16 helpers -------------------------------------------------------------------------
__device__ __forceinline__ float s2f(short s) {
  unsigned v = ((unsigned)(unsigned short)s) << 16;
  return __builtin_bit_cast(float, v);
}
__device__ __forceinline__ short f2s_rne(float f) {
  unsigned u = __builtin_bit_cast(unsigned, f);
  unsigned r = (u + 0x7FFFu + ((u >> 16) & 1u)) >> 16;
  return (short)r;
}
// h = truncated-bf16(f) (residual exactly representable), l = RNE(f - h)
__device__ __forceinline__ void split(float f, short& h, short& l) {
  const unsigned u = __builtin_bit_cast(unsigned, f);
  h = (short)(u >> 16);
  const float fh = __builtin_bit_cast(float, u & 0xFFFF0000u);
  l = f2s_rne(f - fh);
}
__device__ __forceinline__ void split8(const float4 v0, const float4 v1,
                                       bf16x8& hv, bf16x8& lv) {
  const float f[8] = {v0.x, v0.y, v0.z, v0.w, v1.x, v1.y, v1.z, v1.w};
  #pragma unroll
  for (int j = 0; j < 8; ++j) { short hh, ll; split(f[j], hh, ll); hv[j] = hh; lv[j] = ll; }
}

// ---- async global->LDS, 16B per lane ------------------------------------------------------
__device__ __forceinline__ void gload16(const short* g, short* l) {
  __builtin_amdgcn_global_load_lds(
      (const __attribute__((address_space(1))) void*)g,
      (__attribute__((address_space(3))) void*)l, 16, 0, 0);
}

// Quad-XOR swizzle (verified r5/6: 0 bank conflicts): data quad q of row r lives at
// slot quad q ^ ((r>>1)&3). DMA dest linear; SOURCE pre-permuted; ds_read applies XOR.

// ---- stage one K-tile of NP planes (NP*2 loads/wave, chunk = 16 rows) ---------------------
// planes 0,1 = A hi/lo (lda,m0); plane 2(,3) = B (ldb,n0).
template<int NP>
__device__ __forceinline__ void stage_pl(
    const short* __restrict__ Aph, const short* __restrict__ Apl,
    const short* __restrict__ Bph, const short* __restrict__ Bpl,
    const int lda, const int ldb, const int m0, const int n0, const int k0,
    short* lbase, const int w, const int lane)
{
  const int q  = (lane & 3) ^ ((lane >> 3) & 3);
  const int gr = lane >> 2;
  #pragma unroll
  for (int j = 0; j < NP * 2; ++j) {
    const int L = w * (NP * 2) + j;
    const int p = L >> 3, c = L & 7;
    const short* g = (p == 0) ? Aph : (p == 1) ? Apl : (p == 2) ? Bph : Bpl;
    const int r0 = (p < 2) ? m0 : n0;
    const int ld = (p < 2) ? lda : ldb;
    gload16(g + (size_t)(r0 + c * 16 + gr) * ld + k0 + q * 8, lbase + p * PL + c * 512);
  }
}

// ---- pipelined GEMM phase: NT K-steps of 32; NP=3 -> 2 MFMA, NP=4 -> 3 MFMA ---------------
template<int NT, int NP>
__device__ __forceinline__ void gemm_pl(
    const short* __restrict__ Aph, const short* __restrict__ Apl,
    const short* __restrict__ Bph, const short* __restrict__ Bpl,
    const int lda, const int ldb, const int m0, const int n0, const int tid,
    f32x4 (&acc)[4][4], short* lds)
{
  const int lane = tid & 63, w = tid >> 6, wm = w >> 1, wn = w & 1;
  const int BUF = NP * PL;
  stage_pl<NP>(Aph, Apl, Bph, Bpl, lda, ldb, m0, n0, 0,  lds,       w, lane);
  stage_pl<NP>(Aph, Apl, Bph, Bpl, lda, ldb, m0, n0, 32, lds + BUF, w, lane);

  for (int k = 0; k < NT; ++k) {
    if (k + 1 < NT) {          // wait oldest batch only; newest stays in flight
      if constexpr (NP == 3) asm volatile("s_waitcnt vmcnt(6)" ::: "memory");
      else                   asm volatile("s_waitcnt vmcnt(8)" ::: "memory");
    } else {
      asm volatile("s_waitcnt vmcnt(0)" ::: "memory");
    }
    __builtin_amdgcn_s_barrier();          // all waves' batch-k DMA landed

    short* cur = lds + (k & 1) * BUF;
    const int lr = lane & 15, kg = lane >> 4;
    const int qo = (kg ^ ((lr >> 1) & 3)) * 8;
    bf16x8 ah[4], al[4], bh[4], bl[4];
    #pragma unroll
    for (int mi = 0; mi < 4; ++mi) {
      const int ro = (wm * 64 + mi * 16 + lr) * 32 + qo;
      ah[mi] = *(const bf16x8*)&cur[ro];
      al[mi] = *(const bf16x8*)&cur[PL + ro];
    }
    #pragma unroll
    for (int ni = 0; ni < 4; ++ni) {
      const int co = (wn * 64 + ni * 16 + lr) * 32 + qo;
      bh[ni] = *(const bf16x8*)&cur[2 * PL + co];
      if constexpr (NP == 4) bl[ni] = *(const bf16x8*)&cur[3 * PL + co];
    }
    asm volatile("s_waitcnt lgkmcnt(0)" ::: "memory");
    __builtin_amdgcn_s_barrier();          // all waves' reads done -> safe to overwrite

    if (k + 2 < NT)                        // DMA flies under the MFMAs below
      stage_pl<NP>(Aph, Apl, Bph, Bpl, lda, ldb, m0, n0, (k + 2) * 32, cur, w, lane);

    #pragma unroll
    for (int ni = 0; ni < 4; ++ni)
      #pragma unroll
      for (int mi = 0; mi < 4; ++mi) {
        acc[mi][ni] = __builtin_amdgcn_mfma_f32_16x16x32_bf16(ah[mi], bh[ni], acc[mi][ni], 0, 0, 0);
        acc[mi][ni] = __builtin_amdgcn_mfma_f32_16x16x32_bf16(al[mi], bh[ni], acc[mi][ni], 0, 0, 0);
        if constexpr (NP == 4)
          acc[mi][ni] = __builtin_amdgcn_mfma_f32_16x16x32_bf16(ah[mi], bl[ni], acc[mi][ni], 0, 0, 0);
      }
  }
}

// ---- x-fallback: split fp32 regs -> swizzled ds_write -------------------------------------
__device__ __forceinline__ void stageAx(const float4 (&pa)[4], short* Ah, short* Al,
                                        const int r, const int kh)
{
  bf16x8 h0, l0, h1, l1;
  split8(pa[0], pa[1], h0, l0);
  split8(pa[2], pa[3], h1, l1);
  const int f  = (r >> 1) & 3;
  const int q0 = ((2 * kh) ^ f) * 8, q1 = ((2 * kh + 1) ^ f) * 8;
  *(bf16x8*)&Ah[r * 32 + q0] = h0;  *(bf16x8*)&Ah[r * 32 + q1] = h1;
  *(bf16x8*)&Al[r * 32 + q0] = l0;  *(bf16x8*)&Al[r * 32 + q1] = l1;
}

// ---- fallback GEMM (x fp32 on the fly, B single plane), old 2-barrier structure -----------
__device__ __forceinline__ void gemm_fb(
    const float* __restrict__ Af, const short* __restrict__ Bw,
    const int lda, const int ldb, const int K, const int m0, const int n0, const int tid,
    f32x4 (&acc)[4][4], short* lds)    // planes: Ah@0, Al@PL, Bw@2*PL (single buffer)
{
  const int lane = tid & 63, w = tid >> 6, wm = w >> 1, wn = w & 1;
  const int r = tid & 127, kh = tid >> 7;
  short *LAh = lds, *LAl = lds + PL, *LB = lds + 2 * PL;
  float4 pa[4];
  {
    const float* p = Af + (size_t)(m0 + r) * lda + kh * 16;
    #pragma unroll
    for (int i = 0; i < 4; ++i) pa[i] = *(const float4*)(p + 4 * i);
  }
  for (int k0 = 0; k0 < K; k0 += 32) {
    __syncthreads();                       // prev reads done
    stageAx(pa, LAh, LAl, r, kh);
    if (w >= 2) {                          // waves 2,3 stage B (4 chunks each)
      const int q = (lane & 3) ^ ((lane >> 3) & 3);
      const int gr = lane >> 2;
      const int c0 = (w & 1) * 4;
      #pragma unroll
      for (int i = 0; i < 4; ++i)
        gload16(Bw + (size_t)(n0 + (c0 + i) * 16 + gr) * ldb + k0 + q * 8,
                LB + (c0 + i) * 512);
    }
    __syncthreads();                       // full drain (vmcnt+lgkm)
    if (k0 + 32 < K) {
      const float* p = Af + (size_t)(m0 + r) * lda + (k0 + 32) + kh * 16;
      #pragma unroll
      for (int i = 0; i < 4; ++i) pa[i] = *(const float4*)(p + 4 * i);
    }
    const int lr = lane & 15, kg = lane >> 4;
    const int qo = (kg ^ ((lr >> 1) & 3)) * 8;
    bf16x8 ah[4], al[4], bh[4];
    #pragma unroll
    for (int mi = 0; mi < 4; ++mi) {
      const int ro = (wm * 64 + mi * 16 + lr) * 32 + qo;
      ah[mi] = *(const bf16x8*)&LAh[ro];
      al[mi] = *(const bf16x8*)&LAl[ro];
    }
    #pragma unroll
    for (int ni = 0; ni < 4; ++ni)
      bh[ni] = *(const bf16x8*)&LB[(wn * 64 + ni * 16 + lr) * 32 + qo];
    #pragma unroll
    for (int ni = 0; ni < 4; ++ni)
      #pragma unroll
      for (int mi = 0; mi < 4; ++mi) {
        acc[mi][ni] = __builtin_amdgcn_mfma_f32_16x16x32_bf16(ah[mi], bh[ni], acc[mi][ni], 0, 0, 0);
        acc[mi][ni] = __builtin_amdgcn_mfma_f32_16x16x32_bf16(al[mi], bh[ni], acc[mi][ni], 0, 0, 0);
      }
  }
  __syncthreads();                         // protect LDS before caller reuses it
}

// ---- XCD-locality block mapping (verified r6: FETCH -70%) ---------------------------------
__device__ __forceinline__ void map_mn(const int bid, int& mb, int& nb) {
  const int xcd = bid & 7;
  const int j   = bid >> 3;
  mb = xcd * 32 + (j >> 3);
  nb = j & 7;
}

// ---- weight pre-split (hi/lo) and pre-round (single RNE) ----------------------------------
__global__ __launch_bounds__(256) void wsplit_k(const float* __restrict__ src,
    short* __restrict__ h, short* __restrict__ l, const int n4, const float sgn)
{
  const int i = blockIdx.x * 256 + threadIdx.x;
  if (i >= n4) return;
  const float4 v = ((const float4*)src)[i];
  const float f[4] = {sgn * v.x, sgn * v.y, sgn * v.z, sgn * v.w};
  short4 hv, lv;
  split(f[0], hv.x, lv.x); split(f[1], hv.y, lv.y);
  split(f[2], hv.z, lv.z); split(f[3], hv.w, lv.w);
  ((short4*)h)[i] = hv;
  ((short4*)l)[i] = lv;
}
__global__ __launch_bounds__(256) void wround_k(const float* __restrict__ src,
    short* __restrict__ h, const int n4)
{
  const int i = blockIdx.x * 256 + threadIdx.x;
  if (i >= n4) return;
  const float4 v = ((const float4*)src)[i];
  short4 hv;
  hv.x = f2s_rne(v.x); hv.y = f2s_rne(v.y); hv.z = f2s_rne(v.z); hv.w = f2s_rne(v.w);
  ((short4*)h)[i] = hv;
}

// ---- kernel 1: Bu planes = split_bf16(gamma * (x @ [Bre|Bim]^T)), B single-plane ----------
template<bool XAG>
__global__ __launch_bounds__(256, 2) void bu_mfma(
    const float* __restrict__ x, const short* __restrict__ xh, const short* __restrict__ xl,
    const short* __restrict__ Brw, const short* __restrict__ Biw,
    const float* __restrict__ gamma,
    short* __restrict__ re_h, short* __restrict__ re_l,
    short* __restrict__ im_h, short* __restrict__ im_l)
{
  __shared__ short lds[2 * 3 * PL];        // 48 KB
  f32x4 acc[4][4] = {};
  const int tid = threadIdx.x;
  int mb, nbk;
  map_mn(blockIdx.x, mb, nbk);
  const int m0  = mb * 128;
  const int n0s = nbk * 128;
  const bool re = (n0s < NST);
  const int nb0 = n0s & (NST - 1);
  const short* Bw = re ? Brw : Biw;

  if constexpr (XAG)
    gemm_pl<32, 3>(xh, xl, Bw, nullptr, DIN, DIN, m0, nb0, tid, acc, lds);
  else
    gemm_fb(x, Bw, DIN, DIN, DIN, m0, nb0, tid, acc, lds);

  short* Hp = re ? re_h : im_h;
  short* Lp = re ? re_l : im_l;
  const int lane = tid & 63, w = tid >> 6, wm = w >> 1, wn = w & 1;
  const int lr = lane & 15, lq = lane >> 4;
  #pragma unroll
  for (int ni = 0; ni < 4; ++ni) {
    const int nb = nb0 + wn * 64 + ni * 16 + lr;
    const float g = gamma[nb];
    #pragma unroll
    for (int mi = 0; mi < 4; ++mi)
      #pragma unroll
      for (int j = 0; j < 4; ++j) {
        const size_t m = (size_t)m0 + wm * 64 + mi * 16 + lq * 4 + j;
        short hh, ll;
        split(acc[mi][ni][j] * g, hh, ll);
        Hp[m * NST + nb] = hh;
        Lp[m * NST + nb] = ll;
      }
  }
}

// ---- scan params --------------------------------------------------------------------------
__global__ void params_k(const float* __restrict__ nulog, const float* __restrict__ thlog,
                         const float* __restrict__ glog,
                         float2* __restrict__ lam, float2* __restrict__ lamL,
                         float* __restrict__ gamma)
{
  const int n = blockIdx.x * 256 + threadIdx.x;
  if (n >= NST) return;
  const float nu = expf(nulog[n]);
  const float th = expf(thlog[n]);
  const float mod = expf(-nu);
  float s, c;
  sincosf(th, &s, &c);
  lam[n] = make_float2(mod * c, mod * s);
  const float modL = expf(-(float)CL * nu);
  float sL, cL;
  sincosf((float)CL * th, &sL, &cL);
  lamL[n] = make_float2(modL * cL, modL * sL);
  gamma[n] = expf(glog[n]);
}

// ---- scan phase 1 -------------------------------------------------------------------------
__global__ __launch_bounds__(256) void scan_partial(
    const short* __restrict__ re_h, const short* __restrict__ re_l,
    const short* __restrict__ im_h, const short* __restrict__ im_l,
    const float2* __restrict__ lam, float2* __restrict__ carry)
{
  const int g = blockIdx.x * 256 + threadIdx.x;
  const int n = g & (NST - 1);
  const int c = (g >> 9) & (NC - 1);
  const int b = g >> 14;
  const float2 L = lam[n];
  size_t idx = ((size_t)b * TLEN + (size_t)c * CL) * NST + n;
  float sr = 0.f, si = 0.f;
  #pragma unroll 4
  for (int t = 0; t < CL; ++t, idx += NST) {
    const float br = s2f(re_h[idx]) + s2f(re_l[idx]);
    const float bi = s2f(im_h[idx]) + s2f(im_l[idx]);
    const float nr = fmaf(L.x, sr, fmaf(-L.y, si, br));
    const float ni = fmaf(L.x, si, fmaf( L.y, sr, bi));
    sr = nr; si = ni;
  }
  carry[(size_t)(b * NC + c) * NST + n] = make_float2(sr, si);
}

// ---- scan phase 2 -------------------------------------------------------------------------
__global__ __launch_bounds__(256) void scan_carry(
    float2* __restrict__ carry, const float2* __restrict__ lamL)
{
  const int g = blockIdx.x * 256 + threadIdx.x;
  const int n = g & (NST - 1);
  const int b = g >> 9;
  const float2 P = lamL[n];
  float sr = 0.f, si = 0.f;
  for (int c = 0; c < NC; ++c) {
    const size_t idx = (size_t)(b * NC + c) * NST + n;
    const float2 v = carry[idx];
    carry[idx] = make_float2(sr, si);
    const float nr = fmaf(P.x, sr, fmaf(-P.y, si, v.x));
    const float ni = fmaf(P.x, si, fmaf( P.y, sr, v.y));
    sr = nr; si = ni;
  }
}

// ---- scan phase 3 -------------------------------------------------------------------------
__global__ __launch_bounds__(256) void scan_final(
    short* __restrict__ re_h, short* __restrict__ re_l,
    short* __restrict__ im_h, short* __restrict__ im_l,
    const float2* __restrict__ lam, const float2* __restrict__ carry)
{
  const int g = blockIdx.x * 256 + threadIdx.x;
  const int n = g & (NST - 1);
  const int c = (g >> 9) & (NC - 1);
  const int b = g >> 14;
  const float2 L = lam[n];
  const float2 ci = carry[(size_t)(b * NC + c) * NST + n];
  size_t idx = ((size_t)b * TLEN + (size_t)c * CL) * NST + n;
  float sr = ci.x, si = ci.y;
  #pragma unroll 4
  for (int t = 0; t < CL; ++t, idx += NST) {
    const float br = s2f(re_h[idx]) + s2f(re_l[idx]);
    const float bi = s2f(im_h[idx]) + s2f(im_l[idx]);
    const float nr = fmaf(L.x, sr, fmaf(-L.y, si, br));
    const float ni = fmaf(L.x, si, fmaf( L.y, sr, bi));
    sr = nr; si = ni;
    short hh, ll;
    split(sr, hh, ll); re_h[idx] = hh; re_l[idx] = ll;
    split(si, hh, ll); im_h[idx] = hh; im_l[idx] = ll;
  }
}

// ---- kernel 5: y = st_re@Cre^T - st_im@Cim^T + x@D^T --------------------------------------
// C phases: NP=4 (C hi/lo, 3 MFMA); D phase: NP=3 (D single, 2 MFMA).
template<bool XAG>
__global__ __launch_bounds__(256, 2) void out_mfma(
    const short* __restrict__ re_h, const short* __restrict__ re_l,
    const short* __restrict__ im_h, const short* __restrict__ im_l,
    const float* __restrict__ x, const short* __restrict__ xh, const short* __restrict__ xl,
    const short* __restrict__ Crh, const short* __restrict__ Crl,
    const short* __restrict__ Cih, const short* __restrict__ Cil,  // Cim pre-negated
    const short* __restrict__ Dw,
    float* __restrict__ y)
{
  __shared__ short lds[2 * 4 * PL];        // 64 KB
  f32x4 acc[4][4] = {};
  const int tid = threadIdx.x;
  int mb, nbk;
  map_mn(blockIdx.x, mb, nbk);
  const int m0 = mb * 128;
  const int o0 = nbk * 128;

  gemm_pl<16, 4>(re_h, re_l, Crh, Crl, NST, NST, m0, o0, tid, acc, lds);
  gemm_pl<16, 4>(im_h, im_l, Cih, Cil, NST, NST, m0, o0, tid, acc, lds);
  if constexpr (XAG)
    gemm_pl<32, 3>(xh, xl, Dw, nullptr, DIN, DIN, m0, o0, tid, acc, lds);
  else
    gemm_fb(x, Dw, DIN, DIN, DIN, m0, o0, tid, acc, lds);

  const int lane = tid & 63, w = tid >> 6, wm = w >> 1, wn = w & 1;
  const int lr = lane & 15, lq = lane >> 4;
  #pragma unroll
  for (int mi = 0; mi < 4; ++mi)
    #pragma unroll
    for (int j = 0; j < 4; ++j) {
      const size_t m = (size_t)m0 + wm * 64 + mi * 16 + lq * 4 + j;
      #pragma unroll
      for (int ni = 0; ni < 4; ++ni)
        y[m * DOUT + o0 + wn * 64 + ni * 16 + lr] = acc[mi][ni][j];
    }
}

// ---- host launch --------------------------------------------------------------------------
extern "C" void kernel_launch(void* const* d_in, const int* in_sizes, int n_in,
                              void* d_out, int out_size, void* d_ws, size_t ws_size,
                              hipStream_t stream)
{
  (void)in_sizes; (void)n_in; (void)out_size;
  const float* x     = (const float*)d_in[0];
  const float* nulog = (const float*)d_in[1];
  const float* thlog = (const float*)d_in[2];
  const float* glog  = (const float*)d_in[3];
  const float* Bre   = (const float*)d_in[4];
  const float* Bim   = (const float*)d_in[5];
  const float* Cre   = (const float*)d_in[6];
  const float* Cim   = (const float*)d_in[7];
  const float* Dm    = (const float*)d_in[8];
  float* y = (float*)d_out;

  // ws layout: 4 state planes | carry | lam | lamL | gamma | weight planes | [x planes]
  const size_t PLANE  = (size_t)M_TOT * NST;
  const size_t XPLANE = (size_t)M_TOT * DIN;
  short*  re_h  = (short*)d_ws;
  short*  re_l  = re_h + PLANE;
  short*  im_h  = re_l + PLANE;
  short*  im_l  = im_h + PLANE;
  float2* carry = (float2*)(im_l + PLANE);
  float2* lam   = carry + (size_t)BSZ * NC * NST;
  float2* lamL  = lam + NST;
  float*  gamma = (float*)(lamL + NST);

  char* wp = (char*)(gamma + NST);
  wp = (char*)(((uintptr_t)wp + 255) & ~(uintptr_t)255);
  short* Brw = (short*)wp;                          // B single planes
  short* Biw = Brw + (size_t)NST * DIN;
  short* Crh = Biw + (size_t)NST * DIN;             // C hi/lo planes
  short* Crl = Crh + (size_t)DOUT * NST;
  short* Cih = Crl + (size_t)DOUT * NST;
  short* Cil = Cih + (size_t)DOUT * NST;
  short* Dw  = Cil + (size_t)DOUT * NST;            // D single plane
  short* xh  = Dw  + (size_t)DOUT * DIN;
  short* xl  = xh + XPLANE;
  const size_t needed_full = (size_t)((char*)(xl + XPLANE) - (char*)d_ws);
  const bool full = (ws_size >= needed_full);

  params_k<<<2, 256, 0, stream>>>(nulog, thlog, glog, lam, lamL, gamma);

  const int nB4 = (NST * DIN) / 4, nC4 = (DOUT * NST) / 4, nD4 = (DOUT * DIN) / 4;
  wround_k<<<(nB4 + 255) / 256, 256, 0, stream>>>(Bre, Brw, nB4);
  wround_k<<<(nB4 + 255) / 256, 256, 0, stream>>>(Bim, Biw, nB4);
  wsplit_k<<<(nC4 + 255) / 256, 256, 0, stream>>>(Cre, Crh, Crl, nC4,  1.0f);
  wsplit_k<<<(nC4 + 255) / 256, 256, 0, stream>>>(Cim, Cih, Cil, nC4, -1.0f);
  wround_k<<<(nD4 + 255) / 256, 256, 0, stream>>>(Dm, Dw, nD4);

  if (full) {
    const int nX4 = (int)(XPLANE / 4);
    wsplit_k<<<(nX4 + 255) / 256, 256, 0, stream>>>(x, xh, xl, nX4, 1.0f);
    bu_mfma<true><<<2048, 256, 0, stream>>>(
        x, xh, xl, Brw, Biw, gamma, re_h, re_l, im_h, im_l);
  } else {
    bu_mfma<false><<<2048, 256, 0, stream>>>(
        x, xh, xl, Brw, Biw, gamma, re_h, re_l, im_h, im_l);
  }

  scan_partial<<<(BSZ * NC * NST) / 256, 256, 0, stream>>>(re_h, re_l, im_h, im_l, lam, carry);
  scan_carry<<<(BSZ * NST) / 256, 256, 0, stream>>>(carry, lamL);
  scan_final<<<(BSZ * NC * NST) / 256, 256, 0, stream>>>(re_h, re_l, im_h, im_l, lam, carry);

  if (full) {
    out_mfma<true><<<2048, 256, 0, stream>>>(
        re_h, re_l, im_h, im_l, x, xh, xl, Crh, Crl, Cih, Cil, Dw, y);
  } else {
    out_mfma<false><<<2048, 256, 0, stream>>>(
        re_h, re_l, im_h, im_l, x, xh, xl, Crh, Crl, Cih, Cil, Dw, y);
  }
}